// Round 1
// baseline (110.089 us; speedup 1.0000x reference)
//
#include <hip/hip_runtime.h>

// ChaosClock collapses analytically:
//  - teleporter spacing (1024) > T (512)  => no teleporter reachable after t=0
//  - ptr strictly increases, never wraps  => every ring slot written at most once
//  - cur (gathered state) is therefore always 0 => W_hh contributes nothing
//  - final gather state[:, tel, :]: slot 0 = upd@t0, slots 1024/2048/3072 = 0
// => logits = GRU(x[:,0,:] @ Wp.T + bp, h=0) @ Wh[:, :8].T + bh
// jump_rand, W_hh, Wj, bj and x[:, 1:, :] do not affect the output.

#define BATCH 512
#define TLEN  512
#define DIM   64
#define SLOT  8
#define NCLS  1000

__global__ __launch_bounds__(256) void chaos_clock_collapsed(
    const float* __restrict__ x,
    const float* __restrict__ Wp,   const float* __restrict__ bp,
    const float* __restrict__ W_ih, const float* __restrict__ b_ih,
    const float* __restrict__ b_hh,
    const float* __restrict__ Wh,   const float* __restrict__ bh,
    float* __restrict__ out)
{
    __shared__ float s_inp[SLOT];
    __shared__ float s_upd[SLOT];
    const int b = blockIdx.x;
    const int t = threadIdx.x;

    // 1) inp0[s] = bp[s] + sum_d x[b,0,d] * Wp[s,d]   (8 threads, L1-cached reads)
    if (t < SLOT) {
        const float* xb = x + (size_t)b * (TLEN * DIM);   // x[b, 0, :]
        const float* wr = Wp + t * DIM;
        float acc = bp[t];
        #pragma unroll
        for (int d = 0; d < DIM; ++d) acc += xb[d] * wr[d];
        s_inp[t] = acc;
    }
    __syncthreads();

    // 2) GRU cell with h = 0:  gh = b_hh;  upd = (1-z)*n
    if (t < SLOT) {
        float gr = b_ih[t], gz = b_ih[SLOT + t], gn = b_ih[2 * SLOT + t];
        #pragma unroll
        for (int s = 0; s < SLOT; ++s) {
            const float v = s_inp[s];
            gr += W_ih[t * SLOT + s]            * v;
            gz += W_ih[(SLOT + t) * SLOT + s]    * v;
            gn += W_ih[(2 * SLOT + t) * SLOT + s] * v;
        }
        const float r = 1.0f / (1.0f + expf(-(gr + b_hh[t])));
        const float z = 1.0f / (1.0f + expf(-(gz + b_hh[SLOT + t])));
        const float n = tanhf(gn + r * b_hh[2 * SLOT + t]);
        s_upd[t] = (1.0f - z) * n;
    }
    __syncthreads();

    // 3) logits[b,c] = bh[c] + sum_{s<8} upd0[s] * Wh[c, s]  (Wh row stride = 32)
    float u[SLOT];
    #pragma unroll
    for (int s = 0; s < SLOT; ++s) u[s] = s_upd[s];   // LDS broadcast, conflict-free

    for (int c = t; c < NCLS; c += 256) {
        const float* wr = Wh + c * (4 * SLOT);
        float acc = bh[c];
        #pragma unroll
        for (int s = 0; s < SLOT; ++s) acc += u[s] * wr[s];
        out[b * NCLS + c] = acc;                       // coalesced store
    }
}

extern "C" void kernel_launch(void* const* d_in, const int* in_sizes, int n_in,
                              void* d_out, int out_size, void* d_ws, size_t ws_size,
                              hipStream_t stream) {
    const float* x    = (const float*)d_in[0];
    // d_in[1] = jump_rand (int32)  — unused: jumps cannot affect the output
    const float* Wp   = (const float*)d_in[2];
    const float* bp   = (const float*)d_in[3];
    const float* W_ih = (const float*)d_in[4];
    // d_in[5] = W_hh — unused: hidden state is always zero
    const float* b_ih = (const float*)d_in[6];
    const float* b_hh = (const float*)d_in[7];
    // d_in[8] = Wj, d_in[9] = bj — unused: only gate ptr, never the output
    const float* Wh   = (const float*)d_in[10];
    const float* bh   = (const float*)d_in[11];
    float* out = (float*)d_out;

    chaos_clock_collapsed<<<BATCH, 256, 0, stream>>>(
        x, Wp, bp, W_ih, b_ih, b_hh, Wh, bh, out);
}

// Round 2
// 108.983 us; speedup vs baseline: 1.0101x; 1.0101x over previous
//
#include <hip/hip_runtime.h>

// ChaosClock collapses analytically:
//  - teleporter spacing (1024) > T (512)  => no teleporter reachable after t=0
//  - ptr strictly increases, never wraps  => every ring slot written at most once
//  - cur (gathered state) is therefore always 0 => W_hh contributes nothing
//  - final gather state[:, tel, :]: slot 0 = upd@t0, slots 1024/2048/3072 = 0
// => logits = GRU(x[:,0,:] @ Wp.T + bp, h=0) @ Wh[:, :8].T + bh
// jump_rand, W_hh, Wj, bj and x[:, 1:, :] do not affect the output.
//
// R1: 64 blocks x 256 threads, 8 batches/block. Phase A: 64 threads compute
// u[8][8] for the block's batch tile. Phase B: each Wh row load is reused
// across 8 batches (Wh L2 traffic 66 MB -> 8 MB vs R0).

#define BATCH 512
#define TLEN  512
#define DIM   64
#define SLOT  8
#define NCLS  1000
#define NBPB  8          // batches per block

__global__ __launch_bounds__(256) void chaos_clock_collapsed(
    const float* __restrict__ x,
    const float* __restrict__ Wp,   const float* __restrict__ bp,
    const float* __restrict__ W_ih, const float* __restrict__ b_ih,
    const float* __restrict__ b_hh,
    const float* __restrict__ Wh,   const float* __restrict__ bh,
    float* __restrict__ out)
{
    __shared__ float s_inp[NBPB][SLOT];
    __shared__ float s_u[NBPB][SLOT];
    const int t  = threadIdx.x;
    const int b0 = blockIdx.x * NBPB;

    // Phase A1: inp[lb][s] = bp[s] + x[b,0,:] . Wp[s,:]   (64 threads)
    if (t < NBPB * SLOT) {
        const int lb = t >> 3, s = t & 7;
        const float4* xb = (const float4*)(x + (size_t)(b0 + lb) * (TLEN * DIM));
        const float4* wr = (const float4*)(Wp + s * DIM);
        float acc = bp[s];
        #pragma unroll
        for (int d = 0; d < DIM / 4; ++d) {
            const float4 xv = xb[d], wv = wr[d];
            acc += xv.x * wv.x + xv.y * wv.y + xv.z * wv.z + xv.w * wv.w;
        }
        s_inp[lb][s] = acc;
    }
    __syncthreads();

    // Phase A2: GRU cell with h = 0:  gh = b_hh;  u = (1-z)*n   (64 threads)
    if (t < NBPB * SLOT) {
        const int lb = t >> 3, s = t & 7;
        float gr = b_ih[s], gz = b_ih[SLOT + s], gn = b_ih[2 * SLOT + s];
        #pragma unroll
        for (int k = 0; k < SLOT; ++k) {
            const float v = s_inp[lb][k];
            gr += W_ih[s * SLOT + k]             * v;
            gz += W_ih[(SLOT + s) * SLOT + k]     * v;
            gn += W_ih[(2 * SLOT + s) * SLOT + k] * v;
        }
        const float r = 1.0f / (1.0f + expf(-(gr + b_hh[s])));
        const float z = 1.0f / (1.0f + expf(-(gz + b_hh[SLOT + s])));
        const float n = tanhf(gn + r * b_hh[2 * SLOT + s]);
        s_u[lb][s] = (1.0f - z) * n;
    }
    __syncthreads();

    // Phase B: logits[b,c] = bh[c] + u[b,:] . Wh[c,0:8]  (Wh row stride = 32)
    for (int c = t; c < NCLS; c += 256) {
        const float4* wr = (const float4*)(Wh + (size_t)c * (4 * SLOT));
        const float4 w0 = wr[0], w1 = wr[1];
        const float bhc = bh[c];
        #pragma unroll
        for (int lb = 0; lb < NBPB; ++lb) {
            const float* u = s_u[lb];                 // wave-broadcast reads
            float acc = bhc
                + u[0] * w0.x + u[1] * w0.y + u[2] * w0.z + u[3] * w0.w
                + u[4] * w1.x + u[5] * w1.y + u[6] * w1.z + u[7] * w1.w;
            out[(size_t)(b0 + lb) * NCLS + c] = acc;  // coalesced per lb
        }
    }
}

extern "C" void kernel_launch(void* const* d_in, const int* in_sizes, int n_in,
                              void* d_out, int out_size, void* d_ws, size_t ws_size,
                              hipStream_t stream) {
    const float* x    = (const float*)d_in[0];
    // d_in[1] = jump_rand (int32)  — unused: jumps cannot affect the output
    const float* Wp   = (const float*)d_in[2];
    const float* bp   = (const float*)d_in[3];
    const float* W_ih = (const float*)d_in[4];
    // d_in[5] = W_hh — unused: hidden state is always zero
    const float* b_ih = (const float*)d_in[6];
    const float* b_hh = (const float*)d_in[7];
    // d_in[8] = Wj, d_in[9] = bj — unused: only gate ptr, never the output
    const float* Wh   = (const float*)d_in[10];
    const float* bh   = (const float*)d_in[11];
    float* out = (float*)d_out;

    chaos_clock_collapsed<<<BATCH / NBPB, 256, 0, stream>>>(
        x, Wp, bp, W_ih, b_ih, b_hh, Wh, bh, out);
}